// Round 5
// baseline (767.788 us; speedup 1.0000x reference)
//
#include <hip/hip_runtime.h>
#include <hip/hip_bf16.h>
#include <cstdint>
#include <cstddef>

#define NB 1024
#define DM 512
#define NH 8
#define HD 64
#define NT 81
#define O3 1536
#define NP 96

// workspace per-batch layout (u16): V[512][88] | qT[81][512] | kT[81][512]
#define VPAD 88
#define VSZ  (512 * VPAD)          // 45056
#define QTSZ (81 * 512)            // 41472
#define PB   (VSZ + 2 * QTSZ)      // 128000 u16 per batch

typedef __bf16 bf16x8 __attribute__((ext_vector_type(8)));
typedef float  f32x4  __attribute__((ext_vector_type(4)));
typedef unsigned short us8 __attribute__((ext_vector_type(8)));
typedef unsigned short us4 __attribute__((ext_vector_type(4)));

__device__ __forceinline__ unsigned short f2bf(float f) {
    unsigned u = __builtin_bit_cast(unsigned, f);
    u += 0x7fffu + ((u >> 16) & 1u);          // round-to-nearest-even
    return (unsigned short)(u >> 16);
}
__device__ __forceinline__ float bf2f(unsigned short h) {
    unsigned u = ((unsigned)h) << 16;
    return __builtin_bit_cast(float, u);
}
__device__ __forceinline__ bf16x8 ld8(const unsigned short* p) {
    return __builtin_bit_cast(bf16x8, *(const us8*)p);
}
__device__ __forceinline__ void async16(void* lds, const void* g) {
    __builtin_amdgcn_global_load_lds(
        (const __attribute__((address_space(1))) void*)g,
        (__attribute__((address_space(3))) void*)lds, 16, 0, 0);
}

// ---------------- kernel 1: qkv_w fp32 -> bf16 ----------------
__global__ void conv_w(const float* __restrict__ w, unsigned short* __restrict__ wb, int n) {
    int i = blockIdx.x * 256 + threadIdx.x;
    if (i < n) wb[i] = f2bf(w[i]);
}

// ---------------- kernel 1b: x fp32 [b][c][n] -> xT bf16 [b][n=96][c=512] ----------------
__global__ __launch_bounds__(256) void transpose_x(
    const float* __restrict__ x, unsigned short* __restrict__ xT)
{
    __shared__ float sT[64][85];   // stride 85: 2-way (free) banks both phases
    const int tid = threadIdx.x;
    const int b  = blockIdx.x >> 3;
    const int c0 = (blockIdx.x & 7) * 64;
    const float* xb = x + ((size_t)b * DM + c0) * NT;

    const int nn = tid & 31, cc0 = tid >> 5;
    for (int i = 0; i < 8; ++i) {
        int cc = cc0 + i * 8;
        const float* xr = xb + (size_t)cc * NT;
        #pragma unroll
        for (int j = 0; j < 3; ++j) {
            int n = nn + 32 * j;
            if (n < NT) sT[cc][n] = xr[n];
        }
    }
    __syncthreads();

    const int ci = tid & 7, n0 = tid >> 3;    // ci: c-octet, n0: 0..31
    for (int i = 0; i < 3; ++i) {
        int n = n0 + 32 * i;                  // 0..95 (pad rows -> zeros)
        us8 v;
        #pragma unroll
        for (int j = 0; j < 8; ++j) {
            float f = (n < NT) ? sT[ci * 8 + j][n] : 0.f;
            v[j] = f2bf(f);
        }
        *(us8*)(xT + ((size_t)b * NP + n) * DM + c0 + ci * 8) = v;
    }
}

// ---------------- kernel 2a: QKV GEMM — dbuf + XCD swizzle + attention-native output ----------------
// v6 change vs v5: epilogue writes the layouts attention consumes directly:
//   Q,K sections -> transposed [n][512] per batch (packed us4 stores: one wave instr
//   writes 16 rows x 32 B fully-used sectors); V -> [512][88] row-major, pad cols
//   81..87 zeroed (NaN-proofs PV's P=0 x pad products).
// MFMA core, staging, K-order bit-identical to v5.
#define OT 256
#define KC 32

__global__ __launch_bounds__(256, 3) void qkv_gemm_a(
    const unsigned short* __restrict__ xT,
    const unsigned short* __restrict__ wb,
    const float* __restrict__ bias,
    const float* __restrict__ relh,
    const float* __restrict__ relw,
    unsigned short* __restrict__ qkv)
{
    __shared__ __align__(16) unsigned short sW[2][OT * KC];   // 2 x 16 KB
    __shared__ __align__(16) unsigned short sX[2][NP * KC];   // 2 x 6 KB   => 45056 B total

    const int tid  = threadIdx.x;
    const int lane = tid & 63;
    const int wv   = tid >> 6;
    // XCD-chunked swizzle: D%8 = XCD; 6 o-tiles of one b adjacent per XCD.
    const int D    = blockIdx.x;
    const int s    = D >> 3;                  // per-XCD sequence 0..767
    const int b    = (D & 7) * (NB / 8) + s / 6;
    const int ot   = s % 6;
    const int o0   = ot * OT;
    const int r16  = lane & 15;
    const int q8   = (lane >> 4) * 8;
    const int sq8  = q8 ^ ((r16 & 3) * 8);    // swizzled chunk offset (shorts)

    f32x4 acc[4][6];
    #pragma unroll
    for (int i = 0; i < 4; ++i)
        #pragma unroll
        for (int j = 0; j < 6; ++j)
            acc[i][j] = (f32x4){0.f, 0.f, 0.f, 0.f};

    const unsigned short* xb = xT + (size_t)b * NP * DM;

    auto stage = [&](int bi, int kc) {
        unsigned short* dW = &sW[bi][0];
        unsigned short* dX = &sX[bi][0];
        #pragma unroll
        for (int i = 0; i < 4; ++i) {
            int ch  = i * 256 + wv * 64 + lane;
            int row = ch >> 2, cb = ch & 3;
            int cbs = cb ^ (row & 3);
            async16(dW + (i * 256 + wv * 64) * 8,
                    wb + (size_t)(o0 + row) * DM + kc + cbs * 8);
        }
        {
            int ch  = wv * 64 + lane;
            int row = ch >> 2, cb = ch & 3;
            int cbs = cb ^ (row & 3);
            async16(dX + (wv * 64) * 8, xb + (size_t)row * DM + kc + cbs * 8);
            if (wv < 2) {
                int ch2  = 256 + wv * 64 + lane;
                int row2 = ch2 >> 2, cb2 = ch2 & 3;
                int cbs2 = cb2 ^ (row2 & 3);
                async16(dX + (256 + wv * 64) * 8, xb + (size_t)row2 * DM + kc + cbs2 * 8);
            }
        }
    };

    auto compute = [&](const unsigned short* bW, const unsigned short* bX) {
        bf16x8 af[4], bfr[6];
        #pragma unroll
        for (int i = 0; i < 4; ++i)
            af[i] = ld8(&bW[(wv * 64 + i * 16 + r16) * KC + sq8]);
        #pragma unroll
        for (int nt = 0; nt < 6; ++nt)
            bfr[nt] = ld8(&bX[(nt * 16 + r16) * KC + sq8]);
        #pragma unroll
        for (int i = 0; i < 4; ++i)
            #pragma unroll
            for (int nt = 0; nt < 6; ++nt)
                acc[i][nt] = __builtin_amdgcn_mfma_f32_16x16x32_bf16(af[i], bfr[nt], acc[i][nt], 0, 0, 0);
    };

    stage(0, 0);
    __syncthreads();
    for (int ks = 0; ks < 16; ks += 2) {
        stage(1, (ks + 1) * KC);
        compute(&sW[0][0], &sX[0][0]);
        __syncthreads();
        if (ks + 2 < 16) stage(0, (ks + 2) * KC);
        compute(&sW[1][0], &sX[1][0]);
        __syncthreads();
    }

    // ---- epilogue: section-specific layouts ----
    unsigned short* base = qkv + (size_t)b * PB;
    const int sec = ot >> 1;                  // 0=Q, 1=K, 2=V (o0 256-tiles: 0,1|2,3|4,5)
    if (sec < 2) {
        unsigned short* tb = base + VSZ + sec * QTSZ;   // qT or kT, [n][512]
        const int osec = o0 - sec * 512;                // 0 or 256 within section
        #pragma unroll
        for (int i = 0; i < 4; ++i) {
            int obase = osec + (wv * 4 + i) * 16 + (lane >> 4) * 4;
            #pragma unroll
            for (int nt = 0; nt < 6; ++nt) {
                int n = nt * 16 + r16;
                if (n < NT) {
                    us4 pk;
                    #pragma unroll
                    for (int r = 0; r < 4; ++r) {
                        int o = obase + r;                       // within-section channel
                        float v = acc[i][nt][r] + bias[sec * 512 + o];
                        if (sec == 1)
                            v += relh[o * 9 + (n % 9)] + relw[o * 9 + (n / 9)];
                        pk[r] = f2bf(v);
                    }
                    *(us4*)(tb + (size_t)n * 512 + obase) = pk;  // 8-B aligned
                }
            }
        }
    } else {
        unsigned short* vb = base;                               // V [512][88]
        const int osec = o0 - 1024;
        #pragma unroll
        for (int i = 0; i < 4; ++i) {
            int obase = osec + (wv * 4 + i) * 16 + (lane >> 4) * 4;
            #pragma unroll
            for (int nt = 0; nt < 6; ++nt) {
                int n = nt * 16 + r16;
                if (n < VPAD) {
                    #pragma unroll
                    for (int r = 0; r < 4; ++r) {
                        int o = obase + r;
                        unsigned short sv = 0;
                        if (n < NT) sv = f2bf(acc[i][nt][r] + bias[1024 + o]);
                        vb[(size_t)o * VPAD + n] = sv;           // pad cols 81..87 -> 0
                    }
                }
            }
        }
    }
}

// ---------------- kernel 2b: fallback GEMM (round-1 core, new output layout) ----------------
#define OTILE 128
#define SWS 40
#define SXS 40

__global__ __launch_bounds__(256) void qkv_gemm_fb(
    const float* __restrict__ x,
    const unsigned short* __restrict__ wb,
    const float* __restrict__ bias,
    const float* __restrict__ relh,
    const float* __restrict__ relw,
    unsigned short* __restrict__ qkv)
{
    __shared__ unsigned short sW[OTILE * SWS];
    __shared__ unsigned short sXT[NP * SXS];

    const int tid  = threadIdx.x;
    const int lane = tid & 63;
    const int wv   = tid >> 6;
    const int b    = blockIdx.x / (O3 / OTILE);
    const int ot   = blockIdx.x % (O3 / OTILE);
    const int o0   = ot * OTILE;
    const int r16 = lane & 15;
    const int q8  = (lane >> 4) * 8;

    f32x4 acc[2][6];
    for (int i = 0; i < 2; ++i)
        for (int j = 0; j < 6; ++j)
            acc[i][j] = (f32x4){0.f, 0.f, 0.f, 0.f};

    const float* xb = x + (size_t)b * DM * NT;
    const int wr  = tid >> 2;
    const int wc  = (tid & 3) * 8;
    const int xc  = tid >> 3;
    const int xn0 = tid & 7;

    for (int kc = 0; kc < DM; kc += 32) {
        {
            us8 v0 = *(const us8*)(wb + (size_t)(o0 + wr) * DM + kc + wc);
            us8 v1 = *(const us8*)(wb + (size_t)(o0 + wr + 64) * DM + kc + wc);
            *(us8*)(&sW[wr * SWS + wc]) = v0;
            *(us8*)(&sW[(wr + 64) * SWS + wc]) = v1;
        }
        {
            const float* xr = xb + (size_t)(kc + xc) * NT;
            #pragma unroll
            for (int j = 0; j < 12; ++j) {
                int n = xn0 + 8 * j;
                float v = (n < NT) ? xr[n] : 0.f;
                sXT[n * SXS + xc] = f2bf(v);
            }
        }
        __syncthreads();
        bf16x8 af0 = ld8(&sW[((wv * 2 + 0) * 16 + r16) * SWS + q8]);
        bf16x8 af1 = ld8(&sW[((wv * 2 + 1) * 16 + r16) * SWS + q8]);
        #pragma unroll
        for (int nt = 0; nt < 6; ++nt) {
            bf16x8 bfr = ld8(&sXT[(nt * 16 + r16) * SXS + q8]);
            acc[0][nt] = __builtin_amdgcn_mfma_f32_16x16x32_bf16(af0, bfr, acc[0][nt], 0, 0, 0);
            acc[1][nt] = __builtin_amdgcn_mfma_f32_16x16x32_bf16(af1, bfr, acc[1][nt], 0, 0, 0);
        }
        __syncthreads();
    }

    unsigned short* base = qkv + (size_t)b * PB;
    const int sec = ot >> 2;                 // 128-tiles: 0..3=Q, 4..7=K, 8..11=V
    if (sec < 2) {
        unsigned short* tb = base + VSZ + sec * QTSZ;
        const int osec = o0 - sec * 512;
        #pragma unroll
        for (int i = 0; i < 2; ++i) {
            int obase = osec + (wv * 2 + i) * 16 + (lane >> 4) * 4;
            #pragma unroll
            for (int nt = 0; nt < 6; ++nt) {
                int n = nt * 16 + r16;
                if (n < NT) {
                    us4 pk;
                    #pragma unroll
                    for (int r = 0; r < 4; ++r) {
                        int o = obase + r;
                        float v = acc[i][nt][r] + bias[sec * 512 + o];
                        if (sec == 1)
                            v += relh[o * 9 + (n % 9)] + relw[o * 9 + (n / 9)];
                        pk[r] = f2bf(v);
                    }
                    *(us4*)(tb + (size_t)n * 512 + obase) = pk;
                }
            }
        }
    } else {
        unsigned short* vb = base;
        const int osec = o0 - 1024;
        #pragma unroll
        for (int i = 0; i < 2; ++i) {
            int obase = osec + (wv * 2 + i) * 16 + (lane >> 4) * 4;
            #pragma unroll
            for (int nt = 0; nt < 6; ++nt) {
                int n = nt * 16 + r16;
                if (n < VPAD) {
                    #pragma unroll
                    for (int r = 0; r < 4; ++r) {
                        int o = obase + r;
                        unsigned short sv = 0;
                        if (n < NT) sv = f2bf(acc[i][nt][r] + bias[1024 + o]);
                        vb[(size_t)o * VPAD + n] = sv;
                    }
                }
            }
        }
    }
}

// ---------------- kernel 3: attention per (b,h) — v4: zero-staging, zero-barrier ----------------
// 384 threads = 6 waves; wave w owns logit row-tile n in [16w, 16w+16).
// Q^T/K^T/V are pre-formatted by the gemm: MFMA operands load DIRECTLY from global
// (us8, L1/L2-resident slices). Only P round-trips through LDS (wave-private rows).
// Rows n,m in 81..95 clamp to row 80; those logits were already masked to -inf.
// LDS = sP[96][104] + sRcp = 20352 B. No __syncthreads anywhere.
#define SPS 104   // sP row stride (u16)

__global__ __launch_bounds__(384, 4) void attn(
    const unsigned short* __restrict__ qkv,
    float* __restrict__ out)
{
    __shared__ __align__(16) unsigned short sP[96 * SPS];
    __shared__ float sRcp[96];

    const int tid  = threadIdx.x;
    const int lane = tid & 63;
    const int wv   = tid >> 6;                 // 0..5 = this wave's n-tile
    const int c    = lane & 15;                // MFMA C col / frag row index
    const int q    = lane >> 4;                // quad
    const int q8   = q * 8;
    const int b    = blockIdx.x >> 3;
    const int h    = blockIdx.x & 7;

    const unsigned short* vg = qkv + (size_t)b * PB;   // V [512][88]
    const unsigned short* qg = vg + VSZ;               // qT [81][512]
    const unsigned short* kg = qg + QTSZ;              // kT [81][512]
    const int hofs = h * HD;

    // ---- logits: S[n][m], n-tile = wv, 6 m-tiles, K=64 (2 ksteps), operands from global ----
    const int nq = min(wv * 16 + c, 80);               // clamped A-row
    f32x4 acc[6];
    #pragma unroll
    for (int mt = 0; mt < 6; ++mt) acc[mt] = (f32x4){0.f, 0.f, 0.f, 0.f};
    #pragma unroll
    for (int kk = 0; kk < 2; ++kk) {
        bf16x8 qa = ld8(qg + (size_t)nq * 512 + hofs + kk * 32 + q8);
        #pragma unroll
        for (int mt = 0; mt < 6; ++mt) {
            int mrow = (mt * 16 + c < NT) ? (mt * 16 + c) : 80;
            bf16x8 kb = ld8(kg + (size_t)mrow * 512 + hofs + kk * 32 + q8);
            acc[mt] = __builtin_amdgcn_mfma_f32_16x16x32_bf16(qa, kb, acc[mt], 0, 0, 0);
        }
    }
    // mask pad keys: m >= 81 (mt=5, c != 0) -> -inf
    #pragma unroll
    for (int r = 0; r < 4; ++r)
        acc[5][r] = (c == 0) ? acc[5][r] : -3.0e38f;

    // ---- in-register softmax over m; acc becomes UNNORMALIZED fp32 exp ----
    float rcp[4];
    #pragma unroll
    for (int r = 0; r < 4; ++r) {
        float mx = fmaxf(fmaxf(fmaxf(acc[0][r], acc[1][r]), fmaxf(acc[2][r], acc[3][r])),
                         fmaxf(acc[4][r], acc[5][r]));
        mx = fmaxf(mx, __shfl_xor(mx, 1));
        mx = fmaxf(mx, __shfl_xor(mx, 2));
        mx = fmaxf(mx, __shfl_xor(mx, 4));
        mx = fmaxf(mx, __shfl_xor(mx, 8));
        float s = 0.f;
        #pragma unroll
        for (int mt = 0; mt < 6; ++mt) {
            float e = exp2f((acc[mt][r] - mx) * 1.44269504088896f);  // masked -> 0
            acc[mt][r] = e;
            s += bf2f(f2bf(e));          // sum of quantized values (proven numerics)
        }
        s += __shfl_xor(s, 1);
        s += __shfl_xor(s, 2);
        s += __shfl_xor(s, 4);
        s += __shfl_xor(s, 8);
        rcp[r] = 1.0f / s;
    }

    // ---- write UNNORMALIZED P (bf16) to own rows of sP[n][m] (covers all cols 0..95) ----
    #pragma unroll
    for (int mt = 0; mt < 6; ++mt)
        #pragma unroll
        for (int r = 0; r < 4; ++r)
            sP[(wv * 16 + 4 * q + r) * SPS + mt * 16 + c] = f2bf(acc[mt][r]);
    if (c == 0) {
        #pragma unroll
        for (int r = 0; r < 4; ++r)
            sRcp[wv * 16 + 4 * q + r] = rcp[r];
    }
    // wave-private rows: compiler-inserted lgkmcnt orders write->read; no barrier.

    // ---- PV: out[d][n] = (sum_m V[d][m] * P[n][m]) * rcp[n]; V direct from global ----
    f32x4 oacc[4];
    #pragma unroll
    for (int dt = 0; dt < 4; ++dt) oacc[dt] = (f32x4){0.f, 0.f, 0.f, 0.f};
    #pragma unroll
    for (int kt = 0; kt < 3; ++kt) {
        bf16x8 pb = ld8(&sP[(wv * 16 + c) * SPS + kt * 32 + q8]);   // B[k=m][col=n]
        #pragma unroll
        for (int dt = 0; dt < 4; ++dt) {
            bf16x8 va = ld8(vg + (size_t)(hofs + dt * 16 + c) * VPAD + kt * 32 + q8);
            oacc[dt] = __builtin_amdgcn_mfma_f32_16x16x32_bf16(va, pb, oacc[dt], 0, 0, 0);
        }
    }

    // ---- store: oacc[dt][r] = out[d = dt*16 + 4q + r][n = wv*16 + c] ----
    float* ob = out + (size_t)b * DM * NT + (size_t)hofs * NT;
    const int n = wv * 16 + c;
    if (n < NT) {
        float rs = sRcp[n];
        #pragma unroll
        for (int dt = 0; dt < 4; ++dt) {
            #pragma unroll
            for (int r = 0; r < 4; ++r)
                ob[(size_t)(dt * 16 + 4 * q + r) * NT + n] = oacc[dt][r] * rs;
        }
    }
}

extern "C" void kernel_launch(void* const* d_in, const int* in_sizes, int n_in,
                              void* d_out, int out_size, void* d_ws, size_t ws_size,
                              hipStream_t stream) {
    const float* x     = (const float*)d_in[0];
    const float* qkv_w = (const float*)d_in[1];
    const float* qkv_b = (const float*)d_in[2];
    const float* rel_h = (const float*)d_in[3];
    const float* rel_w = (const float*)d_in[4];
    float* out = (float*)d_out;

    // ws layout: qkv' bf16 [1024 * PB] | wb bf16 [1536*512] | xT bf16 [1024*96*512]
    unsigned short* qkv = (unsigned short*)d_ws;
    unsigned short* wb  = qkv + (size_t)NB * PB;
    unsigned short* xT  = wb + (size_t)O3 * DM;
    size_t need = ((size_t)NB * PB + (size_t)O3 * DM + (size_t)NB * NP * DM) * 2;

    conv_w<<<dim3((O3 * DM + 255) / 256), dim3(256), 0, stream>>>(qkv_w, wb, O3 * DM);
    if (ws_size >= need) {
        transpose_x<<<dim3(NB * 8), dim3(256), 0, stream>>>(x, xT);
        qkv_gemm_a<<<dim3(NB * 6), dim3(256), 0, stream>>>(xT, wb, qkv_b, rel_h, rel_w, qkv);
    } else {
        qkv_gemm_fb<<<dim3(NB * 12), dim3(256), 0, stream>>>(x, wb, qkv_b, rel_h, rel_w, qkv);
    }
    attn<<<dim3(NB * NH), dim3(384), 0, stream>>>(qkv, out);
}